// Round 6
// baseline (1361.399 us; speedup 1.0000x reference)
//
#include <hip/hip_runtime.h>
#include <hip/hip_bf16.h>
#include <hip/hip_fp16.h>
#include <stdint.h>

#define CCH 128  // channels
#define FINAL_SCALE 268435456.0f  // 16^7: undo 7 steps of 1/16 scaling (step 8 unscaled)
#define RND 2048      // edges per partition round
#define MAXBUK 128    // buckets = row>>10 -> ceil(100000/1024)=98

// ---------------- CSR build ----------------

__global__ void hist_kernel(const int* __restrict__ rows, int* __restrict__ counts, int E) {
    int stride = gridDim.x * blockDim.x;
    for (int e = blockIdx.x * blockDim.x + threadIdx.x; e < E; e += stride)
        atomicAdd(&counts[rows[e]], 1);
}

// Phase A: per-block (1024) inclusive scan -> row_ptr[i+1] (tile-local), block sum -> partials
__global__ __launch_bounds__(1024) void scanA_kernel(const int* __restrict__ counts,
                                                     int* __restrict__ row_ptr,
                                                     int* __restrict__ partials, int n) {
    __shared__ int tile[1024];
    int t = threadIdx.x;
    int i = blockIdx.x * 1024 + t;
    tile[t] = (i < n) ? counts[i] : 0;
    __syncthreads();
    for (int off = 1; off < 1024; off <<= 1) {
        int add = (t >= off) ? tile[t - off] : 0;
        __syncthreads();
        tile[t] += add;
        __syncthreads();
    }
    if (i < n) row_ptr[i + 1] = tile[t];
    if (t == 1023) partials[blockIdx.x] = tile[1023];
}

// Phase B: single block scans partials (nb <= 1024) in place -> exclusive offsets
__global__ __launch_bounds__(1024) void scanB_kernel(int* __restrict__ partials,
                                                     int* __restrict__ row_ptr, int nb) {
    __shared__ int tile[1024];
    int t = threadIdx.x;
    tile[t] = (t < nb) ? partials[t] : 0;
    __syncthreads();
    for (int off = 1; off < 1024; off <<= 1) {
        int add = (t >= off) ? tile[t - off] : 0;
        __syncthreads();
        tile[t] += add;
        __syncthreads();
    }
    if (t < nb) partials[t] = (t == 0) ? 0 : tile[t - 1];
    if (t == 0) row_ptr[0] = 0;
}

// Phase C: add block offsets
__global__ void scanC_kernel(const int* __restrict__ partials, int* __restrict__ row_ptr, int n) {
    int i = blockIdx.x * blockDim.x + threadIdx.x;
    if (i < n) row_ptr[i + 1] += partials[i >> 10];
}

// gcur[b] = start of bucket b's region in the final CSR edge array
__global__ void gcur_init_kernel(const int* __restrict__ row_ptr, int* __restrict__ gcur,
                                 int nbuk, int n) {
    int b = threadIdx.x;
    if (b < nbuk) {
        int r = b << 10;
        gcur[b] = row_ptr[r < n ? r : n];
    }
}

// Pass 1: counting-sort 2048-edge rounds by bucket (row>>10) in LDS, stream out
// bucket-grouped 16 B records (row,col,val,pad) -> coalesced writes, no 64 B
// write-allocate amplification.
__global__ __launch_bounds__(256) void part_kernel(const int* __restrict__ rows,
                                                   const int* __restrict__ cols,
                                                   const float* __restrict__ vals,
                                                   int* __restrict__ gcur,
                                                   int4* __restrict__ recs,
                                                   int E, int nbuk) {
    __shared__ int hist[MAXBUK];
    __shared__ int offs[MAXBUK];
    __shared__ int cur[MAXBUK];
    __shared__ int gbase[MAXBUK];
    __shared__ int4 stage[RND];  // 32 KB

    int base = blockIdx.x * RND;
    int cnt = E - base;
    if (cnt > RND) cnt = RND;
    if (cnt <= 0) return;

    for (int i = threadIdx.x; i < nbuk; i += 256) hist[i] = 0;
    __syncthreads();

    int myr[RND / 256], myc[RND / 256];
    float myv[RND / 256];
#pragma unroll
    for (int k = 0; k < RND / 256; ++k) {
        int li = k * 256 + threadIdx.x;
        bool ok = li < cnt;
        int gi = base + li;
        myr[k] = ok ? rows[gi] : -1;
        myc[k] = ok ? cols[gi] : 0;
        myv[k] = ok ? vals[gi] : 0.f;
        if (ok) atomicAdd(&hist[myr[k] >> 10], 1);
    }
    __syncthreads();

    if (threadIdx.x == 0) {  // serial exclusive scan over <=98 buckets
        int run = 0;
        for (int b = 0; b < nbuk; ++b) {
            offs[b] = run;
            cur[b] = run;
            run += hist[b];
        }
    }
    __syncthreads();
    if (threadIdx.x < nbuk) gbase[threadIdx.x] = atomicAdd(&gcur[threadIdx.x], hist[threadIdx.x]);
    __syncthreads();

#pragma unroll
    for (int k = 0; k < RND / 256; ++k) {
        if (myr[k] >= 0) {
            int b = myr[k] >> 10;
            int p = atomicAdd(&cur[b], 1);
            stage[p] = make_int4(myr[k], myc[k], __float_as_int(myv[k]), 0);
        }
    }
    __syncthreads();

    for (int i = threadIdx.x; i < cnt; i += 256) {
        int4 r = stage[i];
        int b = r.x >> 10;
        recs[(size_t)gbase[b] + (i - offs[b])] = r;
    }
}

// Pass 2: scatter bucket-grouped records to exact CSR slots. Each bucket's
// destination region (~260 KB) is L2-resident -> stores merge into full lines.
__global__ __launch_bounds__(256) void csrfill_kernel(const int4* __restrict__ recs,
                                                      const int* __restrict__ row_ptr,
                                                      int* __restrict__ fill,
                                                      int2* __restrict__ edges,
                                                      int n) {
    int bucket = blockIdx.x >> 3, slice = blockIdx.x & 7;
    int r0 = bucket << 10;
    int r1 = r0 + 1024;
    if (r0 > n) return;
    if (r1 > n) r1 = n;
    int bstart = row_ptr[r0];
    int bend = row_ptr[r1];
    int cnt = bend - bstart;
    int per = (cnt + 7) >> 3;
    int s = bstart + slice * per;
    int e = s + per;
    if (e > bend) e = bend;
    for (int i = s + threadIdx.x; i < e; i += 256) {
        int4 r = recs[i];
        int pos = row_ptr[r.x] + atomicAdd(&fill[r.x], 1);
        edges[pos] = make_int2(r.y, r.z);
    }
}

// ---------------- GEMM: t0 = x @ W, stored fp16  (x:[N,128], W:[128,128]) ----------------

#define GEMM_ROWS 64

__global__ __launch_bounds__(256) void gemm_kernel(const float* __restrict__ x,
                                                   const float* __restrict__ w,
                                                   __half* __restrict__ out, int n) {
    __shared__ __half2 wl[CCH * 64];  // [k][col_pair], 32 KB
    for (int i = threadIdx.x; i < CCH * 64 / 2; i += 256) {
        float4 v = ((const float4*)w)[i];
        wl[2 * i]     = __float22half2_rn(make_float2(v.x, v.y));
        wl[2 * i + 1] = __float22half2_rn(make_float2(v.z, v.w));
    }
    __syncthreads();

    int tc = threadIdx.x & 31;
    int tr = threadIdx.x >> 5;
    int rbase = blockIdx.x * GEMM_ROWS + tr * 8;
    int nr = n - rbase;
    if (nr > 8) nr = 8;
    if (nr <= 0) nr = 0;

    float acc[8][4] = {};
    const float* xp = x + (size_t)rbase * CCH;

    float4 xc[8];
#pragma unroll
    for (int j = 0; j < 8; ++j)
        xc[j] = (j < nr) ? *(const float4*)(xp + (size_t)j * CCH)
                         : make_float4(0.f, 0.f, 0.f, 0.f);

    for (int k = 0; k < CCH; k += 4) {
        float4 xn[8];
        if (k + 4 < CCH) {
#pragma unroll
            for (int j = 0; j < 8; ++j)
                xn[j] = (j < nr) ? *(const float4*)(xp + (size_t)j * CCH + k + 4)
                                 : make_float4(0.f, 0.f, 0.f, 0.f);
        }
#pragma unroll
        for (int kk = 0; kk < 4; ++kk) {
            __half2 w01 = wl[(k + kk) * 64 + tc * 2];
            __half2 w23 = wl[(k + kk) * 64 + tc * 2 + 1];
            float2 f01 = __half22float2(w01);
            float2 f23 = __half22float2(w23);
#pragma unroll
            for (int j = 0; j < 8; ++j) {
                float xs = (kk == 0) ? xc[j].x : (kk == 1) ? xc[j].y : (kk == 2) ? xc[j].z : xc[j].w;
                acc[j][0] += xs * f01.x;
                acc[j][1] += xs * f01.y;
                acc[j][2] += xs * f23.x;
                acc[j][3] += xs * f23.y;
            }
        }
        if (k + 4 < CCH) {
#pragma unroll
            for (int j = 0; j < 8; ++j) xc[j] = xn[j];
        }
    }
#pragma unroll
    for (int j = 0; j < 8; ++j)
        if (j < nr) {
            __half2* orow = (__half2*)(out + (size_t)(rbase + j) * CCH + tc * 4);
            orow[0] = __float22half2_rn(make_float2(acc[j][0], acc[j][1]));
            orow[1] = __float22half2_rn(make_float2(acc[j][2], acc[j][3]));
        }
}

// ---------------- SpMM (fp16 src): dst[row] = (1/16) * sum_e val_e * src[col_e] ----------
// One row per wave; 4 groups of 16 lanes each process their own edge with a
// dwordx4 gather -> 4 edges per VMEM instruction, 16 edges in flight per wave.

template <int FINAL>
__global__ __launch_bounds__(256) void spmm_kernel(const int* __restrict__ row_ptr,
                                                   const int2* __restrict__ edges,
                                                   const __half* __restrict__ src,
                                                   __half* __restrict__ dsth,
                                                   float* __restrict__ dstf,
                                                   const float* __restrict__ identity,
                                                   int n) {
    int lane = threadIdx.x & 63;
    int row = (blockIdx.x * blockDim.x + threadIdx.x) >> 6;
    if (row >= n) return;
    int g = lane >> 4;
    int gl = lane & 15;

    int s = row_ptr[row];
    int e = row_ptr[row + 1];

    float acc[8] = {};

    for (int base = s; base < e; base += 16) {
        int2 ed[4];
        float4 gv[4];
#pragma unroll
        for (int t = 0; t < 4; ++t) {
            int idx = base + g * 4 + t;
            bool ok = idx < e;
            ed[t] = edges[ok ? idx : s];
            if (!ok) ed[t].y = 0;
        }
#pragma unroll
        for (int t = 0; t < 4; ++t)
            gv[t] = *(const float4*)(src + (size_t)ed[t].x * CCH + gl * 8);
#pragma unroll
        for (int t = 0; t < 4; ++t) {
            float v = __int_as_float(ed[t].y);
            const __half* h = (const __half*)&gv[t];
#pragma unroll
            for (int j = 0; j < 8; ++j)
                acc[j] += v * __half2float(h[j]);
        }
    }

#pragma unroll
    for (int j = 0; j < 8; ++j) {
        acc[j] += __shfl_xor(acc[j], 16, 64);
        acc[j] += __shfl_xor(acc[j], 32, 64);
    }

    if (FINAL) {
        if (g == 0) {
            const float* iv = identity + (size_t)row * CCH + gl * 8;
            float4 o;
            o.x = iv[0] + acc[0] * FINAL_SCALE;
            o.y = iv[1] + acc[1] * FINAL_SCALE;
            o.z = iv[2] + acc[2] * FINAL_SCALE;
            o.w = iv[3] + acc[3] * FINAL_SCALE;
            *(float4*)(dstf + (size_t)row * CCH + gl * 8) = o;
        } else if (g == 1) {
            const float* iv = identity + (size_t)row * CCH + gl * 8 + 4;
            float4 o;
            o.x = iv[0] + acc[4] * FINAL_SCALE;
            o.y = iv[1] + acc[5] * FINAL_SCALE;
            o.z = iv[2] + acc[6] * FINAL_SCALE;
            o.w = iv[3] + acc[7] * FINAL_SCALE;
            *(float4*)(dstf + (size_t)row * CCH + gl * 8 + 4) = o;
        }
    } else {
        if (g == 0) {
            __half2 h[4];
            h[0] = __float22half2_rn(make_float2(acc[0] * 0.0625f, acc[1] * 0.0625f));
            h[1] = __float22half2_rn(make_float2(acc[2] * 0.0625f, acc[3] * 0.0625f));
            h[2] = __float22half2_rn(make_float2(acc[4] * 0.0625f, acc[5] * 0.0625f));
            h[3] = __float22half2_rn(make_float2(acc[6] * 0.0625f, acc[7] * 0.0625f));
            *(float4*)(dsth + (size_t)row * CCH + gl * 8) = *(float4*)h;
        }
    }
}

// ---------------- launch ----------------

static inline size_t align256(size_t x) { return (x + 255) & ~(size_t)255; }

extern "C" void kernel_launch(void* const* d_in, const int* in_sizes, int n_in,
                              void* d_out, int out_size, void* d_ws, size_t ws_size,
                              hipStream_t stream) {
    const float* x = (const float*)d_in[0];
    const float* w = (const float*)d_in[1];
    const float* lap_vals = (const float*)d_in[2];
    const int* lap_rows = (const int*)d_in[3];
    const int* lap_cols = (const int*)d_in[4];

    const int N = in_sizes[0] / CCH;     // 100000
    const int E = in_sizes[2];           // 3200000
    const int NB = (N + 1023) / 1024;    // scan blocks
    const int NBUK = (N + 1023) >> 10;   // partition buckets (98)

    // workspace layout
    char* ws = (char*)d_ws;
    size_t off = 0;
    __half* bufA = (__half*)(ws + off); off = align256(off + (size_t)N * CCH * sizeof(__half));
    __half* bufB = (__half*)(ws + off); off = align256(off + (size_t)N * CCH * sizeof(__half));
    int2* edges = (int2*)(ws + off);    off = align256(off + (size_t)E * sizeof(int2));
    int* row_ptr = (int*)(ws + off);    off = align256(off + (size_t)(N + 1) * sizeof(int));
    int* counts = (int*)(ws + off);     off = align256(off + (size_t)N * sizeof(int));
    int* fill = (int*)(ws + off);       off = align256(off + (size_t)N * sizeof(int));
    int* partials = (int*)(ws + off);   off = align256(off + (size_t)NB * sizeof(int));
    int* gcur = (int*)(ws + off);       off = align256(off + (size_t)MAXBUK * sizeof(int));
    (void)ws_size;
    // recs aliases bufA+bufB (E*16 = 51.2 MB <= 2*N*CCH*2 = 51.2 MB); only live
    // between part_kernel and csrfill_kernel, both before gemm writes bufA.
    int4* recs = (int4*)bufA;

    float* out = (float*)d_out;

    hipMemsetAsync(counts, 0, (size_t)N * sizeof(int), stream);
    hipMemsetAsync(fill, 0, (size_t)N * sizeof(int), stream);

    // CSR build
    hist_kernel<<<2048, 256, 0, stream>>>(lap_rows, counts, E);
    scanA_kernel<<<NB, 1024, 0, stream>>>(counts, row_ptr, partials, N);
    scanB_kernel<<<1, 1024, 0, stream>>>(partials, row_ptr, NB);
    scanC_kernel<<<(N + 255) / 256, 256, 0, stream>>>(partials, row_ptr, N);
    gcur_init_kernel<<<1, MAXBUK, 0, stream>>>(row_ptr, gcur, NBUK, N);
    part_kernel<<<(E + RND - 1) / RND, 256, 0, stream>>>(lap_rows, lap_cols, lap_vals,
                                                         gcur, recs, E, NBUK);
    csrfill_kernel<<<NBUK * 8, 256, 0, stream>>>(recs, row_ptr, fill, edges, N);

    // GEMM -> bufA (fp16 t0)
    gemm_kernel<<<(N + GEMM_ROWS - 1) / GEMM_ROWS, 256, 0, stream>>>(x, w, bufA, N);

    // steps 1..7 fp16 ping-pong (each scaled 1/16), step 8 fp32 -> d_out (+identity, x16^7)
    int spmm_blocks = (N + 3) / 4;  // 1 row per wave, 4 waves per 256-thread block
    const __half* src = bufA;
    __half* dst = bufB;
    for (int step = 1; step <= 7; ++step) {
        spmm_kernel<0><<<spmm_blocks, 256, 0, stream>>>(row_ptr, edges, src, dst, nullptr, nullptr, N);
        __half* t = (__half*)src;
        src = dst;
        dst = t;
    }
    spmm_kernel<1><<<spmm_blocks, 256, 0, stream>>>(row_ptr, edges, src, nullptr, out, x, N);
}

// Round 7
// 1258.453 us; speedup vs baseline: 1.0818x; 1.0818x over previous
//
#include <hip/hip_runtime.h>
#include <hip/hip_bf16.h>
#include <hip/hip_fp16.h>
#include <stdint.h>

#define CCH 128  // channels
#define FINAL_SCALE 268435456.0f  // 16^7: undo 7 steps of 1/16 scaling (step 8 unscaled)
#define RND 2048      // edges per partition round
#define BUKSH 9       // bucket = row >> 9 (512 rows/bucket)
#define BUKROWS 512
#define MAXBUK 256    // ceil(100000/512)=196

// ---------------- CSR build ----------------

__global__ void hist_kernel(const int* __restrict__ rows, int* __restrict__ counts, int E) {
    int stride = gridDim.x * blockDim.x;
    for (int e = blockIdx.x * blockDim.x + threadIdx.x; e < E; e += stride)
        atomicAdd(&counts[rows[e]], 1);
}

// Phase A: per-block (1024) inclusive scan -> row_ptr[i+1] (tile-local), block sum -> partials
__global__ __launch_bounds__(1024) void scanA_kernel(const int* __restrict__ counts,
                                                     int* __restrict__ row_ptr,
                                                     int* __restrict__ partials, int n) {
    __shared__ int tile[1024];
    int t = threadIdx.x;
    int i = blockIdx.x * 1024 + t;
    tile[t] = (i < n) ? counts[i] : 0;
    __syncthreads();
    for (int off = 1; off < 1024; off <<= 1) {
        int add = (t >= off) ? tile[t - off] : 0;
        __syncthreads();
        tile[t] += add;
        __syncthreads();
    }
    if (i < n) row_ptr[i + 1] = tile[t];
    if (t == 1023) partials[blockIdx.x] = tile[1023];
}

// Phase B: single block scans partials (nb <= 1024) in place -> exclusive offsets
__global__ __launch_bounds__(1024) void scanB_kernel(int* __restrict__ partials,
                                                     int* __restrict__ row_ptr, int nb) {
    __shared__ int tile[1024];
    int t = threadIdx.x;
    tile[t] = (t < nb) ? partials[t] : 0;
    __syncthreads();
    for (int off = 1; off < 1024; off <<= 1) {
        int add = (t >= off) ? tile[t - off] : 0;
        __syncthreads();
        tile[t] += add;
        __syncthreads();
    }
    if (t < nb) partials[t] = (t == 0) ? 0 : tile[t - 1];
    if (t == 0) row_ptr[0] = 0;
}

// Phase C: add block offsets
__global__ void scanC_kernel(const int* __restrict__ partials, int* __restrict__ row_ptr, int n) {
    int i = blockIdx.x * blockDim.x + threadIdx.x;
    if (i < n) row_ptr[i + 1] += partials[i >> 10];
}

// gcur[b] = start of bucket b's region in the final CSR edge array
__global__ void gcur_init_kernel(const int* __restrict__ row_ptr, int* __restrict__ gcur,
                                 int nbuk, int n) {
    int b = threadIdx.x;
    if (b < nbuk) {
        int r = b << BUKSH;
        gcur[b] = row_ptr[r < n ? r : n];
    }
}

// Pass 1: counting-sort 2048-edge rounds by bucket (row>>9) in LDS, stream out
// bucket-grouped 16 B records (row,col,val,pad) -> mostly-coalesced writes.
__global__ __launch_bounds__(256) void part_kernel(const int* __restrict__ rows,
                                                   const int* __restrict__ cols,
                                                   const float* __restrict__ vals,
                                                   int* __restrict__ gcur,
                                                   int4* __restrict__ recs,
                                                   int E, int nbuk) {
    __shared__ int hist[MAXBUK];
    __shared__ int offs[MAXBUK];
    __shared__ int cur[MAXBUK];
    __shared__ int gbase[MAXBUK];
    __shared__ int4 stage[RND];  // 32 KB

    int base = blockIdx.x * RND;
    int cnt = E - base;
    if (cnt > RND) cnt = RND;
    if (cnt <= 0) return;

    for (int i = threadIdx.x; i < nbuk; i += 256) hist[i] = 0;
    __syncthreads();

    int myr[RND / 256], myc[RND / 256];
    float myv[RND / 256];
#pragma unroll
    for (int k = 0; k < RND / 256; ++k) {
        int li = k * 256 + threadIdx.x;
        bool ok = li < cnt;
        int gi = base + li;
        myr[k] = ok ? rows[gi] : -1;
        myc[k] = ok ? cols[gi] : 0;
        myv[k] = ok ? vals[gi] : 0.f;
        if (ok) atomicAdd(&hist[myr[k] >> BUKSH], 1);
    }
    __syncthreads();

    if (threadIdx.x == 0) {  // serial exclusive scan over <=196 buckets
        int run = 0;
        for (int b = 0; b < nbuk; ++b) {
            offs[b] = run;
            cur[b] = run;
            run += hist[b];
        }
    }
    __syncthreads();
    if (threadIdx.x < nbuk) gbase[threadIdx.x] = atomicAdd(&gcur[threadIdx.x], hist[threadIdx.x]);
    __syncthreads();

#pragma unroll
    for (int k = 0; k < RND / 256; ++k) {
        if (myr[k] >= 0) {
            int b = myr[k] >> BUKSH;
            int p = atomicAdd(&cur[b], 1);
            stage[p] = make_int4(myr[k], myc[k], __float_as_int(myv[k]), 0);
        }
    }
    __syncthreads();

    for (int i = threadIdx.x; i < cnt; i += 256) {
        int4 r = stage[i];
        int b = r.x >> BUKSH;
        recs[(size_t)gbase[b] + (i - offs[b])] = r;
    }
}

// Pass 2: one block per bucket. All stores for the bucket's ~130 KB CSR region
// come from ONE CU (one XCD L2) -> lines merge and write back full, once.
// fill counters live in LDS (no global atomics, no memset).
__global__ __launch_bounds__(512) void csrfill_kernel(const int4* __restrict__ recs,
                                                      const int* __restrict__ row_ptr,
                                                      int2* __restrict__ edges,
                                                      int n) {
    __shared__ int lfill[BUKROWS];
    int bucket = blockIdx.x;
    int r0 = bucket << BUKSH;
    int r1 = r0 + BUKROWS;
    if (r0 >= n) return;
    if (r1 > n) r1 = n;
    for (int i = threadIdx.x; i < BUKROWS; i += 512) lfill[i] = 0;
    __syncthreads();
    int bstart = row_ptr[r0];
    int bend = row_ptr[r1];
    int i = bstart + threadIdx.x;
    for (; i + 512 < bend; i += 1024) {
        int4 a = recs[i];
        int4 b = recs[i + 512];
        int pa = row_ptr[a.x] + atomicAdd(&lfill[a.x - r0], 1);
        int pb = row_ptr[b.x] + atomicAdd(&lfill[b.x - r0], 1);
        edges[pa] = make_int2(a.y, a.z);
        edges[pb] = make_int2(b.y, b.z);
    }
    if (i < bend) {
        int4 a = recs[i];
        int pa = row_ptr[a.x] + atomicAdd(&lfill[a.x - r0], 1);
        edges[pa] = make_int2(a.y, a.z);
    }
}

// ---------------- GEMM: t0 = x @ W, stored fp16  (x:[N,128], W:[128,128]) ----------------

#define GEMM_ROWS 64

__global__ __launch_bounds__(256) void gemm_kernel(const float* __restrict__ x,
                                                   const float* __restrict__ w,
                                                   __half* __restrict__ out, int n) {
    __shared__ __half2 wl[CCH * 64];  // [k][col_pair], 32 KB
    for (int i = threadIdx.x; i < CCH * 64 / 2; i += 256) {
        float4 v = ((const float4*)w)[i];
        wl[2 * i]     = __float22half2_rn(make_float2(v.x, v.y));
        wl[2 * i + 1] = __float22half2_rn(make_float2(v.z, v.w));
    }
    __syncthreads();

    int tc = threadIdx.x & 31;
    int tr = threadIdx.x >> 5;
    int rbase = blockIdx.x * GEMM_ROWS + tr * 8;
    int nr = n - rbase;
    if (nr > 8) nr = 8;
    if (nr <= 0) nr = 0;

    float acc[8][4] = {};
    const float* xp = x + (size_t)rbase * CCH;

    float4 xc[8];
#pragma unroll
    for (int j = 0; j < 8; ++j)
        xc[j] = (j < nr) ? *(const float4*)(xp + (size_t)j * CCH)
                         : make_float4(0.f, 0.f, 0.f, 0.f);

    for (int k = 0; k < CCH; k += 4) {
        float4 xn[8];
        if (k + 4 < CCH) {
#pragma unroll
            for (int j = 0; j < 8; ++j)
                xn[j] = (j < nr) ? *(const float4*)(xp + (size_t)j * CCH + k + 4)
                                 : make_float4(0.f, 0.f, 0.f, 0.f);
        }
#pragma unroll
        for (int kk = 0; kk < 4; ++kk) {
            __half2 w01 = wl[(k + kk) * 64 + tc * 2];
            __half2 w23 = wl[(k + kk) * 64 + tc * 2 + 1];
            float2 f01 = __half22float2(w01);
            float2 f23 = __half22float2(w23);
#pragma unroll
            for (int j = 0; j < 8; ++j) {
                float xs = (kk == 0) ? xc[j].x : (kk == 1) ? xc[j].y : (kk == 2) ? xc[j].z : xc[j].w;
                acc[j][0] += xs * f01.x;
                acc[j][1] += xs * f01.y;
                acc[j][2] += xs * f23.x;
                acc[j][3] += xs * f23.y;
            }
        }
        if (k + 4 < CCH) {
#pragma unroll
            for (int j = 0; j < 8; ++j) xc[j] = xn[j];
        }
    }
#pragma unroll
    for (int j = 0; j < 8; ++j)
        if (j < nr) {
            __half2* orow = (__half2*)(out + (size_t)(rbase + j) * CCH + tc * 4);
            orow[0] = __float22half2_rn(make_float2(acc[j][0], acc[j][1]));
            orow[1] = __float22half2_rn(make_float2(acc[j][2], acc[j][3]));
        }
}

// ---------------- SpMM (fp16 src): dst[row] = (1/16) * sum_e val_e * src[col_e] ----------
// One row per wave; 4 groups of 16 lanes each process their own edge with a
// dwordx4 gather -> 4 edges per VMEM instruction, 16 edges in flight per wave.

template <int FINAL>
__global__ __launch_bounds__(256) void spmm_kernel(const int* __restrict__ row_ptr,
                                                   const int2* __restrict__ edges,
                                                   const __half* __restrict__ src,
                                                   __half* __restrict__ dsth,
                                                   float* __restrict__ dstf,
                                                   const float* __restrict__ identity,
                                                   int n) {
    int lane = threadIdx.x & 63;
    int row = (blockIdx.x * blockDim.x + threadIdx.x) >> 6;
    if (row >= n) return;
    int g = lane >> 4;
    int gl = lane & 15;

    int s = row_ptr[row];
    int e = row_ptr[row + 1];

    float acc[8] = {};

    for (int base = s; base < e; base += 16) {
        int2 ed[4];
        float4 gv[4];
#pragma unroll
        for (int t = 0; t < 4; ++t) {
            int idx = base + g * 4 + t;
            bool ok = idx < e;
            ed[t] = edges[ok ? idx : s];
            if (!ok) ed[t].y = 0;
        }
#pragma unroll
        for (int t = 0; t < 4; ++t)
            gv[t] = *(const float4*)(src + (size_t)ed[t].x * CCH + gl * 8);
#pragma unroll
        for (int t = 0; t < 4; ++t) {
            float v = __int_as_float(ed[t].y);
            const __half* h = (const __half*)&gv[t];
#pragma unroll
            for (int j = 0; j < 8; ++j)
                acc[j] += v * __half2float(h[j]);
        }
    }

#pragma unroll
    for (int j = 0; j < 8; ++j) {
        acc[j] += __shfl_xor(acc[j], 16, 64);
        acc[j] += __shfl_xor(acc[j], 32, 64);
    }

    if (FINAL) {
        if (g == 0) {
            const float* iv = identity + (size_t)row * CCH + gl * 8;
            float4 o;
            o.x = iv[0] + acc[0] * FINAL_SCALE;
            o.y = iv[1] + acc[1] * FINAL_SCALE;
            o.z = iv[2] + acc[2] * FINAL_SCALE;
            o.w = iv[3] + acc[3] * FINAL_SCALE;
            *(float4*)(dstf + (size_t)row * CCH + gl * 8) = o;
        } else if (g == 1) {
            const float* iv = identity + (size_t)row * CCH + gl * 8 + 4;
            float4 o;
            o.x = iv[0] + acc[4] * FINAL_SCALE;
            o.y = iv[1] + acc[5] * FINAL_SCALE;
            o.z = iv[2] + acc[6] * FINAL_SCALE;
            o.w = iv[3] + acc[7] * FINAL_SCALE;
            *(float4*)(dstf + (size_t)row * CCH + gl * 8 + 4) = o;
        }
    } else {
        if (g == 0) {
            __half2 h[4];
            h[0] = __float22half2_rn(make_float2(acc[0] * 0.0625f, acc[1] * 0.0625f));
            h[1] = __float22half2_rn(make_float2(acc[2] * 0.0625f, acc[3] * 0.0625f));
            h[2] = __float22half2_rn(make_float2(acc[4] * 0.0625f, acc[5] * 0.0625f));
            h[3] = __float22half2_rn(make_float2(acc[6] * 0.0625f, acc[7] * 0.0625f));
            *(float4*)(dsth + (size_t)row * CCH + gl * 8) = *(float4*)h;
        }
    }
}

// ---------------- launch ----------------

static inline size_t align256(size_t x) { return (x + 255) & ~(size_t)255; }

extern "C" void kernel_launch(void* const* d_in, const int* in_sizes, int n_in,
                              void* d_out, int out_size, void* d_ws, size_t ws_size,
                              hipStream_t stream) {
    const float* x = (const float*)d_in[0];
    const float* w = (const float*)d_in[1];
    const float* lap_vals = (const float*)d_in[2];
    const int* lap_rows = (const int*)d_in[3];
    const int* lap_cols = (const int*)d_in[4];

    const int N = in_sizes[0] / CCH;        // 100000
    const int E = in_sizes[2];              // 3200000
    const int NB = (N + 1023) / 1024;       // scan blocks
    const int NBUK = (N + BUKROWS - 1) >> BUKSH;  // 196

    // workspace layout
    char* ws = (char*)d_ws;
    size_t off = 0;
    __half* bufA = (__half*)(ws + off); off = align256(off + (size_t)N * CCH * sizeof(__half));
    __half* bufB = (__half*)(ws + off); off = align256(off + (size_t)N * CCH * sizeof(__half));
    int2* edges = (int2*)(ws + off);    off = align256(off + (size_t)E * sizeof(int2));
    int* row_ptr = (int*)(ws + off);    off = align256(off + (size_t)(N + 1) * sizeof(int));
    int* counts = (int*)(ws + off);     off = align256(off + (size_t)N * sizeof(int));
    int* partials = (int*)(ws + off);   off = align256(off + (size_t)NB * sizeof(int));
    int* gcur = (int*)(ws + off);       off = align256(off + (size_t)MAXBUK * sizeof(int));
    (void)ws_size;
    // recs aliases bufA+bufB (E*16 = 51.2 MB <= 2*N*CCH*2 = 51.2 MB); only live
    // between part_kernel and csrfill_kernel, both before gemm writes bufA.
    int4* recs = (int4*)bufA;

    float* out = (float*)d_out;

    hipMemsetAsync(counts, 0, (size_t)N * sizeof(int), stream);

    // CSR build
    hist_kernel<<<2048, 256, 0, stream>>>(lap_rows, counts, E);
    scanA_kernel<<<NB, 1024, 0, stream>>>(counts, row_ptr, partials, N);
    scanB_kernel<<<1, 1024, 0, stream>>>(partials, row_ptr, NB);
    scanC_kernel<<<(N + 255) / 256, 256, 0, stream>>>(partials, row_ptr, N);
    gcur_init_kernel<<<1, MAXBUK, 0, stream>>>(row_ptr, gcur, NBUK, N);
    part_kernel<<<(E + RND - 1) / RND, 256, 0, stream>>>(lap_rows, lap_cols, lap_vals,
                                                         gcur, recs, E, NBUK);
    csrfill_kernel<<<NBUK, 512, 0, stream>>>(recs, row_ptr, edges, N);

    // GEMM -> bufA (fp16 t0)
    gemm_kernel<<<(N + GEMM_ROWS - 1) / GEMM_ROWS, 256, 0, stream>>>(x, w, bufA, N);

    // steps 1..7 fp16 ping-pong (each scaled 1/16), step 8 fp32 -> d_out (+identity, x16^7)
    int spmm_blocks = (N + 3) / 4;  // 1 row per wave, 4 waves per 256-thread block
    const __half* src = bufA;
    __half* dst = bufB;
    for (int step = 1; step <= 7; ++step) {
        spmm_kernel<0><<<spmm_blocks, 256, 0, stream>>>(row_ptr, edges, src, dst, nullptr, nullptr, N);
        __half* t = (__half*)src;
        src = dst;
        dst = t;
    }
    spmm_kernel<1><<<spmm_blocks, 256, 0, stream>>>(row_ptr, edges, src, nullptr, out, x, N);
}